// Round 6
// baseline (8001.289 us; speedup 1.0000x reference)
//
#include <hip/hip_runtime.h>

typedef __bf16 bf16;
typedef __attribute__((ext_vector_type(8))) __bf16 bf16x8;
typedef __attribute__((ext_vector_type(4))) __bf16 bf16x4;
typedef __attribute__((ext_vector_type(4))) float f32x4;
typedef __attribute__((ext_vector_type(4))) int i32x4;

#define B_TOT 16384
#define SEQ 50
#define DH 512
#define ZW 2048  // 4*DH
#define NT 16    // K-tiles of 32 (K = 512)

#define MFMA16(a, b, c) __builtin_amdgcn_mfma_f32_16x16x32_bf16(a, b, c, 0, 0, 0)

__device__ __forceinline__ float fsigm(float x) {
    return __fdividef(1.0f, 1.0f + __expf(-x));
}
__device__ __forceinline__ float ftanh(float x) {
    float e = __expf(2.0f * x);
    return 1.0f - __fdividef(2.0f, e + 1.0f);
}

__device__ __forceinline__ void gload16(const bf16* g, void* l) {
    __builtin_amdgcn_global_load_lds(
        (const __attribute__((address_space(1))) unsigned int*)g,
        (__attribute__((address_space(3))) unsigned int*)l, 16, 0, 0);
}

// ---------------------------------------------------------------------------
// Setup kernels
// ---------------------------------------------------------------------------

__global__ void init_state(const float* __restrict__ sh,
                           bf16* __restrict__ h0m, bf16* __restrict__ h0y) {
    size_t i = (size_t)blockIdx.x * 256 + threadIdx.x;
    bf16 hb = (bf16)sh[i];
    h0m[i] = hb;
    h0y[i] = hb;
}

// cT[hcol][row] = sc[row][hcol], duplicated into cM and cY. LDS-tiled 64x64.
__global__ void transpose_c(const float* __restrict__ src,
                            float* __restrict__ dM, float* __restrict__ dY) {
    __shared__ float tile[64][65];
    const int tx = blockIdx.x;  // row tile 0..255
    const int ty = blockIdx.y;  // col tile 0..7
    const int lr = threadIdx.x & 63;
    const int lw = threadIdx.x >> 6;
#pragma unroll
    for (int rr = lw; rr < 64; rr += 4)
        tile[rr][lr] = src[(size_t)(tx * 64 + rr) * DH + ty * 64 + lr];
    __syncthreads();
#pragma unroll
    for (int rr = lw; rr < 64; rr += 4) {
        float v = tile[lr][rr];
        size_t o = (size_t)(ty * 64 + rr) * B_TOT + tx * 64 + lr;
        dM[o] = v;
        dY[o] = v;
    }
}

// Column reorder: col' = jb*64 + gate*16 + jj  <->  orig col = gate*512 + jb*16 + jj
__device__ __forceinline__ int orig_col(int colp) {
    return ((colp >> 4) & 3) * 512 + ((colp >> 6) << 4) + (colp & 15);
}

// B in MFMA-fragment layout: frag[cb(128)][kt(16)][lane(64)][e(8)] bf16,
// where colp = cb*16 + (lane&15), k = kt*32 + (lane>>4)*8 + e.
__global__ void reorder_weights(const float* __restrict__ Um, const float* __restrict__ Uy,
                                const float* __restrict__ Wm, const float* __restrict__ Wy,
                                bf16* __restrict__ UtM, bf16* __restrict__ UtY,
                                bf16* __restrict__ WtM, bf16* __restrict__ WtY) {
    int idx = blockIdx.x * 256 + threadIdx.x;
    int which = idx >> 20;
    int r = idx & ((1 << 20) - 1);
    int colp = r >> 9, k = r & 511;
    int orig = orig_col(colp);
    const float* src = which == 0 ? Um : which == 1 ? Uy : which == 2 ? Wm : Wy;
    bf16* dst = which == 0 ? UtM : which == 1 ? UtY : which == 2 ? WtM : WtY;
    int cb = colp >> 4, fr = colp & 15;
    int kt = k >> 5, fq = (k >> 3) & 3, e = k & 7;
    int lane = fq * 16 + fr;
    dst[(((size_t)(cb * 16 + kt) * 64 + lane) << 3) + e] = (bf16)src[(size_t)k * ZW + orig];
}

// Wc2[hcol][r(3)][g(4)] f32
__global__ void build_wc2(const float* __restrict__ Wm, const float* __restrict__ Wy,
                          float* __restrict__ Wc2M, float* __restrict__ Wc2Y) {
    int idx = blockIdx.x * 256 + threadIdx.x;
    if (idx >= 2 * 512 * 12) return;
    int which = idx / 6144;
    int r2 = idx % 6144;
    int hcol = r2 / 12, rg = r2 % 12;
    int r = rg >> 2, g = rg & 3;
    const float* src = which ? Wy : Wm;
    float* dst = which ? Wc2Y : Wc2M;
    dst[hcol * 12 + rg] = src[(size_t)(512 + r) * ZW + g * 512 + hcol];
}

// condT4[t][row][4] f32
__global__ void cond_transpose(const float* __restrict__ cond, float* __restrict__ condT4) {
    int idx = blockIdx.x * 256 + threadIdx.x;
    if (idx >= SEQ * B_TOT) return;
    int t = idx / B_TOT, row = idx % B_TOT;
    const float* s = cond + ((size_t)row * SEQ + t) * 3;
    f32x4 v = {s[0], s[1], s[2], 0.f};
    *(f32x4*)(condT4 + (size_t)idx * 4) = v;
}

__global__ void build_heads(const float* __restrict__ Whm, const float* __restrict__ bhm,
                            const float* __restrict__ Why, const float* __restrict__ bhy,
                            bf16* __restrict__ WhmT, bf16* __restrict__ WhyT,
                            float* __restrict__ tscm, float* __restrict__ tscy) {
    int i = blockIdx.x * 256 + threadIdx.x;
    const int N1 = 32 * 512, N2 = 16 * 512, N3 = SEQ * 32, N4 = SEQ * 16;
    if (i < N1) {
        int n = i >> 9, k = i & 511;
        WhmT[i] = (bf16)(n < 30 ? Whm[k * 30 + n] : 0.f);
    } else if (i < N1 + N2) {
        int j = i - N1;
        int n = j >> 9, k = j & 511;
        WhyT[j] = (bf16)(n < 15 ? Why[k * 15 + n] : 0.f);
    } else if (i < N1 + N2 + N3) {
        int j = i - (N1 + N2);
        int tt = j >> 5, col = j & 31;
        float v = 0.f;
        if (col < 30) {
            v = bhm[col];
            for (int s = 0; s <= tt; ++s) v += Whm[(512 + s) * 30 + col];
        }
        tscm[j] = v;
    } else if (i < N1 + N2 + N3 + N4) {
        int j = i - (N1 + N2 + N3);
        int tt = j >> 4, col = j & 15;
        float v = 0.f;
        if (col < 15) {
            v = bhy[col];
            for (int s = 0; s <= tt; ++s) v += Why[(512 + s) * 15 + col];
        }
        tscy[j] = v;
    }
}

// ---------------------------------------------------------------------------
// Main GEMM: 128x128 tile, BK=32, 4 waves (2x2).
//  - A staged via global_load_lds into a 3-buffer LDS ring (24 KiB).
//  - B loaded from global (fragment layout, L2-resident) via inline asm,
//    double-buffered in registers one tile ahead; counted vmcnt(6).
//  - 4 blocks/CU (launch_bounds(256,4)): 16 waves/CU for latency hiding.
//  - XCD-aware (bx,by) swizzle: each XCD owns a 16-wide bx band (A+B fit L2).
//  - Transposed cT[hcol][row] f32 and xw2[hcol][row][4g] bf16 -> vectorized
//    b128 epilogue loads/stores.
// MODE 0: xw precompute into xw2. MODE 1: LSTM step with fused gate epilogue.
// ---------------------------------------------------------------------------

#define FENCE() asm volatile("" ::: "memory")
#define BARRIER()                        \
    do {                                 \
        FENCE();                         \
        __builtin_amdgcn_s_barrier();    \
        FENCE();                         \
    } while (0)
#define WAIT_LGKM0()                                          \
    do {                                                      \
        asm volatile("s_waitcnt lgkmcnt(0)" ::: "memory");    \
        __builtin_amdgcn_sched_barrier(0);                    \
    } while (0)
#define WAIT_VM(n)                                                  \
    do {                                                            \
        asm volatile("s_waitcnt vmcnt(" #n ")" ::: "memory");       \
        __builtin_amdgcn_sched_barrier(0);                          \
    } while (0)

template <int MODE>
__global__ __launch_bounds__(256, 4) void gemm_step(
    const bf16* __restrict__ Am, const bf16* __restrict__ Ay,
    const bf16* __restrict__ BtM, const bf16* __restrict__ BtY,
    const bf16* __restrict__ xwM, const bf16* __restrict__ xwY,
    const float* __restrict__ Wc2M, const float* __restrict__ Wc2Y,
    const float* __restrict__ biasM, const float* __restrict__ biasY,
    float* __restrict__ cM, float* __restrict__ cY,
    bf16* __restrict__ hoM, bf16* __restrict__ hoY,
    bf16* __restrict__ xoM, bf16* __restrict__ xoY,
    const float* __restrict__ condT4, int t) {
    __shared__ bf16 As[3][128][32];  // 24 KiB ring

    const int tid = threadIdx.x;
    const int wave = tid >> 6, lane = tid & 63;
    // XCD-aware swizzle: lin%8 = XCD; each XCD gets bx in [xcd*16, xcd*16+16)
    // iterating all by per bx -> A-stripe (2MB) + B (2MB) resident in its L2.
    const int lin = blockIdx.y * 128 + blockIdx.x;  // 0..2047
    const int xcd = lin & 7, jj = lin >> 3;
    const int bx = xcd * 16 + (jj >> 4);
    const int by = jj & 15;
    const int brow = bx * 128;
    const int bz = blockIdx.z;
    const bf16* A = bz ? Ay : Am;
    const bf16* Bt = bz ? BtY : BtM;  // fragment layout

    const int fr = lane & 15, fq = lane >> 4;
    const int wr = wave >> 1, wc = wave & 1;

    // A staging: inverse-swizzled global source, linear LDS dest
    const int srow = tid >> 2;                               // 0..63
    const int sc8 = (((tid & 3) ^ ((srow >> 1) & 3)) << 3);  // element offset
    const bf16* Asrc = A + (size_t)(brow + srow) * DH + sc8;
    char* stA = (char*)As + wave * 1024;  // + slot*8192 (+4096 for rows 64..127)

    // A reads: swizzled chunk
    const int cxor = ((fq ^ ((fr >> 1) & 3)) << 4);
    const char* Ard = (char*)As + (wr * 64 + fr) * 64 + cxor;

    // B fragment base: cb0 = by*8 + wc*4 ; addr(n,kt) = bbase + n*16384 + kt*1024
    const uint64_t bbase =
        (uint64_t)(const char*)Bt + (uint64_t)(by * 8 + wc * 4) * 16384 + lane * 16;

    f32x4 acc[4][4];
#pragma unroll
    for (int m = 0; m < 4; ++m)
#pragma unroll
        for (int n = 0; n < 4; ++n) acc[m][n] = (f32x4){0.f, 0.f, 0.f, 0.f};

    i32x4 bgbuf[2][4];

#define STAGE(slot, kts)                                    \
    do {                                                    \
        const bf16* _s = Asrc + (kts) * 32;                 \
        char* _d = stA + (slot) * 8192;                     \
        gload16(_s, _d);                                    \
        gload16(_s + 64 * DH, _d + 4096);                   \
    } while (0)

#define BGLOAD(bank, kts)                                                        \
    do {                                                                         \
        uint64_t _a = bbase + (uint64_t)(kts) * 1024;                            \
        asm volatile("global_load_dwordx4 %0, %1, off"                          \
                     : "=&v"(bgbuf[bank][0]) : "v"(_a) : "memory");              \
        asm volatile("global_load_dwordx4 %0, %1, off"                          \
                     : "=&v"(bgbuf[bank][1]) : "v"(_a + 16384) : "memory");      \
        asm volatile("global_load_dwordx4 %0, %1, off"                          \
                     : "=&v"(bgbuf[bank][2]) : "v"(_a + 32768) : "memory");      \
        asm volatile("global_load_dwordx4 %0, %1, off"                          \
                     : "=&v"(bgbuf[bank][3]) : "v"(_a + 49152) : "memory");      \
    } while (0)

    // prologue: queue = [bg0:4][s0:2][s1:2]; vmcnt(2) retires bg0+s0.
    BGLOAD(0, 0);
    STAGE(0, 0);
    STAGE(1, 1);
    WAIT_VM(2);
    BARRIER();

    // steady state entering tile kt: outstanding = [s(kt+1):2][bg(kt):4]
#pragma unroll
    for (int kt = 0; kt < NT - 1; ++kt) {
        const int rcur = kt % 3;
        STAGE((kt + 2) % 3, (kt + 2 < NT) ? kt + 2 : NT - 1);
        BGLOAD((kt + 1) & 1, kt + 1);
        bf16x8 af[4];
        {
            const char* _a = Ard + rcur * 8192;
            af[0] = *(const bf16x8*)(_a);
            af[1] = *(const bf16x8*)(_a + 1024);
            af[2] = *(const bf16x8*)(_a + 2048);
            af[3] = *(const bf16x8*)(_a + 3072);
        }
        WAIT_LGKM0();
        WAIT_VM(6);  // retires s(kt+1) + bg(kt); leaves s(kt+2) + bg(kt+1)
        __builtin_amdgcn_s_setprio(1);
#pragma unroll
        for (int m = 0; m < 4; ++m)
#pragma unroll
            for (int n = 0; n < 4; ++n)
                acc[m][n] = MFMA16(af[m], __builtin_bit_cast(bf16x8, bgbuf[kt & 1][n]),
                                   acc[m][n]);
        __builtin_amdgcn_s_setprio(0);
        __builtin_amdgcn_sched_barrier(0);
        BARRIER();
    }
    {  // tail tile NT-1
        bf16x8 af[4];
        const char* _a = Ard + ((NT - 1) % 3) * 8192;
        af[0] = *(const bf16x8*)(_a);
        af[1] = *(const bf16x8*)(_a + 1024);
        af[2] = *(const bf16x8*)(_a + 2048);
        af[3] = *(const bf16x8*)(_a + 3072);
        WAIT_LGKM0();
        WAIT_VM(0);
        __builtin_amdgcn_s_setprio(1);
#pragma unroll
        for (int m = 0; m < 4; ++m)
#pragma unroll
            for (int n = 0; n < 4; ++n)
                acc[m][n] = MFMA16(af[m], __builtin_bit_cast(bf16x8, bgbuf[(NT - 1) & 1][n]),
                                   acc[m][n]);
        __builtin_amdgcn_s_setprio(0);
        __builtin_amdgcn_sched_barrier(0);
    }

    const int jb = by * 2 + wc;     // 0..31
    const int hcol = jb * 16 + fr;  // 0..511
    const int rowbase = brow + wr * 64 + fq * 4;

    if (MODE == 0) {
        const float* bias = bz ? biasY : biasM;
        bf16* XO = bz ? xoY : xoM;
        float b0 = bias[hcol], b1 = bias[512 + hcol], b2 = bias[1024 + hcol],
              b3 = bias[1536 + hcol];
#pragma unroll
        for (int m = 0; m < 4; ++m) {
            const int row0 = rowbase + m * 16;
            bf16x8 v0, v1;
#pragma unroll
            for (int j = 0; j < 2; ++j) {
                v0[j * 4 + 0] = (bf16)(acc[m][0][j] + b0);
                v0[j * 4 + 1] = (bf16)(acc[m][1][j] + b1);
                v0[j * 4 + 2] = (bf16)(acc[m][2][j] + b2);
                v0[j * 4 + 3] = (bf16)(acc[m][3][j] + b3);
            }
#pragma unroll
            for (int j = 2; j < 4; ++j) {
                v1[(j - 2) * 4 + 0] = (bf16)(acc[m][0][j] + b0);
                v1[(j - 2) * 4 + 1] = (bf16)(acc[m][1][j] + b1);
                v1[(j - 2) * 4 + 2] = (bf16)(acc[m][2][j] + b2);
                v1[(j - 2) * 4 + 3] = (bf16)(acc[m][3][j] + b3);
            }
            bf16* o = XO + ((size_t)hcol * B_TOT + row0) * 4;
            *(bf16x8*)(o) = v0;
            *(bf16x8*)(o + 8) = v1;
        }
    } else {
        float* Cb = bz ? cY : cM;
        bf16* Ho = bz ? hoY : hoM;
        const bf16* xw = bz ? xwY : xwM;
        const float* Wc2 = bz ? Wc2Y : Wc2M;
        f32x4 wcv0 = *(const f32x4*)(Wc2 + hcol * 12);
        f32x4 wcv1 = *(const f32x4*)(Wc2 + hcol * 12 + 4);
        f32x4 wcv2 = *(const f32x4*)(Wc2 + hcol * 12 + 8);
#pragma unroll
        for (int m = 0; m < 4; ++m) {
            const int row0 = rowbase + m * 16;
            const bf16* xp = xw + ((size_t)hcol * B_TOT + row0) * 4;
            bf16x8 xv0 = *(const bf16x8*)(xp);
            bf16x8 xv1 = *(const bf16x8*)(xp + 8);
            f32x4 cvm = *(const f32x4*)(Cb + (size_t)hcol * B_TOT + row0);
            f32x4 cd[4];
#pragma unroll
            for (int j = 0; j < 4; ++j)
                cd[j] = *(const f32x4*)(condT4 + ((size_t)t * B_TOT + row0 + j) * 4);
            f32x4 cnew;
#pragma unroll
            for (int j = 0; j < 4; ++j) {
                float z[4];
#pragma unroll
                for (int g = 0; g < 4; ++g) {
                    float xwv = (j < 2) ? (float)xv0[j * 4 + g] : (float)xv1[(j - 2) * 4 + g];
                    z[g] = acc[m][g][j] + xwv + cd[j][0] * wcv0[g] + cd[j][1] * wcv1[g] +
                           cd[j][2] * wcv2[g];
                }
                float ii = fsigm(z[0]);
                float ff = fsigm(z[1]);
                float gg = ftanh(z[2]);
                float oo = fsigm(z[3]);
                float cn = ff * cvm[j] + ii * gg;
                cnew[j] = cn;
                Ho[(size_t)(row0 + j) * DH + hcol] = (bf16)(oo * ftanh(cn));
            }
            *(f32x4*)(Cb + (size_t)hcol * B_TOT + row0) = cnew;
        }
    }
#undef STAGE
#undef BGLOAD
}

// ---------------------------------------------------------------------------
// Heads: 512 blocks x 128 threads; 2 waves/block, 16 rows per wave.
// ---------------------------------------------------------------------------
__global__ __launch_bounds__(128) void heads_step(
    const bf16* __restrict__ hm, const bf16* __restrict__ hy,
    const bf16* __restrict__ WhmT, const bf16* __restrict__ WhyT,
    const float* __restrict__ tscm, const float* __restrict__ tscy,
    float* __restrict__ out, int t) {
    __shared__ float zbuf[2 * 768];
    const int tid = threadIdx.x, wave = tid >> 6, lane = tid & 63;
    const int fr = lane & 15, fq = lane >> 4;
    const int rbase = blockIdx.x * 32 + wave * 16;

    f32x4 am0 = {0.f, 0.f, 0.f, 0.f}, am1 = {0.f, 0.f, 0.f, 0.f}, ay0 = {0.f, 0.f, 0.f, 0.f};

    for (int k0 = 0; k0 < DH; k0 += 32) {
        const size_t ao = (size_t)(rbase + fr) * DH + k0 + fq * 8;
        bf16x8 a0 = *(const bf16x8*)(hm + ao);
        bf16x8 y0 = *(const bf16x8*)(hy + ao);
        const size_t bo = (size_t)fr * DH + k0 + fq * 8;
        bf16x8 b0 = *(const bf16x8*)(WhmT + bo);
        bf16x8 b1 = *(const bf16x8*)(WhmT + bo + 16 * DH);
        bf16x8 yb = *(const bf16x8*)(WhyT + bo);
        am0 = MFMA16(a0, b0, am0);
        am1 = MFMA16(a0, b1, am1);
        ay0 = MFMA16(y0, yb, ay0);
    }

    float* zm = zbuf + wave * 768;  // [16][32]
    float* zy = zm + 512;           // [16][16]
#pragma unroll
    for (int j = 0; j < 4; ++j) {
        int rl = fq * 4 + j;
        zm[rl * 32 + fr] = am0[j] + tscm[t * 32 + fr];
        zm[rl * 32 + 16 + fr] = am1[j] + tscm[t * 32 + 16 + fr];
        zy[rl * 16 + fr] = ay0[j] + tscy[t * 16 + fr];
    }
    __syncthreads();

    const int r = lane & 15;
    const size_t grow = (size_t)rbase + r;
    if (lane < 16) {
        float z[30];
#pragma unroll
        for (int i = 0; i < 30; ++i) z[i] = zm[r * 32 + i];
        float* o = out + (grow * SEQ + t) * 30;
        float mx = z[0];
#pragma unroll
        for (int i = 1; i < 5; ++i) mx = fmaxf(mx, z[i]);
        float e[5], s = 0.f;
#pragma unroll
        for (int i = 0; i < 5; ++i) {
            e[i] = __expf(z[i] - mx);
            s += e[i];
        }
        float inv = __fdividef(1.f, s);
#pragma unroll
        for (int i = 0; i < 5; ++i) o[i] = e[i] * inv;
#pragma unroll
        for (int i = 5; i < 10; ++i) o[i] = z[i];
#pragma unroll
        for (int i = 10; i < 15; ++i) o[i] = __expf(z[i]);
#pragma unroll
        for (int i = 15; i < 20; ++i) o[i] = z[i];
#pragma unroll
        for (int i = 20; i < 25; ++i) o[i] = __expf(z[i]);
#pragma unroll
        for (int i = 25; i < 30; ++i) o[i] = ftanh(z[i]);
    } else if (lane < 32) {
        float z[15];
#pragma unroll
        for (int i = 0; i < 15; ++i) z[i] = zy[r * 16 + i];
        float* o = out + (size_t)B_TOT * SEQ * 30 + (grow * SEQ + t) * 15;
        float mx = z[0];
#pragma unroll
        for (int i = 1; i < 5; ++i) mx = fmaxf(mx, z[i]);
        float e[5], s = 0.f;
#pragma unroll
        for (int i = 0; i < 5; ++i) {
            e[i] = __expf(z[i] - mx);
            s += e[i];
        }
        float inv = __fdividef(1.f, s);
#pragma unroll
        for (int i = 0; i < 5; ++i) o[i] = e[i] * inv;
#pragma unroll
        for (int i = 5; i < 10; ++i) o[i] = z[i];
#pragma unroll
        for (int i = 10; i < 15; ++i) o[i] = __expf(z[i]);
    }
}

// ---------------------------------------------------------------------------
extern "C" void kernel_launch(void* const* d_in, const int* in_sizes, int n_in,
                              void* d_out, int out_size, void* d_ws, size_t ws_size,
                              hipStream_t stream) {
    const float* cond = (const float*)d_in[0];
    const float* sh = (const float*)d_in[1];
    const float* sc = (const float*)d_in[2];
    const float* Wm = (const float*)d_in[3];
    const float* Um = (const float*)d_in[4];
    const float* bm = (const float*)d_in[5];
    const float* Whm = (const float*)d_in[6];
    const float* bhm = (const float*)d_in[7];
    const float* Wy = (const float*)d_in[8];
    const float* Uy = (const float*)d_in[9];
    const float* by_ = (const float*)d_in[10];
    const float* Why = (const float*)d_in[11];
    const float* bhy = (const float*)d_in[12];
    float* out = (float*)d_out;

    char* p = (char*)d_ws;
    auto take = [&](size_t bytes) {
        char* r = p;
        p += (bytes + 255) & ~(size_t)255;
        return r;
    };
    bf16* UtM = (bf16*)take((size_t)ZW * DH * 2);
    bf16* UtY = (bf16*)take((size_t)ZW * DH * 2);
    bf16* WtM = (bf16*)take((size_t)ZW * DH * 2);
    bf16* WtY = (bf16*)take((size_t)ZW * DH * 2);
    float* Wc2M = (float*)take(512 * 12 * 4);
    float* Wc2Y = (float*)take(512 * 12 * 4);
    bf16* WhmT = (bf16*)take(32 * DH * 2);
    bf16* WhyT = (bf16*)take(16 * DH * 2);
    float* tscm = (float*)take(SEQ * 32 * 4);
    float* tscy = (float*)take(SEQ * 16 * 4);
    float* condT4 = (float*)take((size_t)SEQ * B_TOT * 4 * 4);
    bf16* xwM = (bf16*)take((size_t)B_TOT * ZW * 2);
    bf16* xwY = (bf16*)take((size_t)B_TOT * ZW * 2);
    bf16* hM0 = (bf16*)take((size_t)B_TOT * DH * 2);
    bf16* hM1 = (bf16*)take((size_t)B_TOT * DH * 2);
    bf16* hY0 = (bf16*)take((size_t)B_TOT * DH * 2);
    bf16* hY1 = (bf16*)take((size_t)B_TOT * DH * 2);
    float* cMb = (float*)take((size_t)B_TOT * DH * 4);
    float* cYb = (float*)take((size_t)B_TOT * DH * 4);
    bf16* hM[2] = {hM0, hM1};
    bf16* hY[2] = {hY0, hY1};

    init_state<<<(B_TOT * DH) / 256, 256, 0, stream>>>(sh, hM0, hY0);
    transpose_c<<<dim3(B_TOT / 64, DH / 64), 256, 0, stream>>>(sc, cMb, cYb);
    reorder_weights<<<(4 * ZW * DH) / 256, 256, 0, stream>>>(Um, Uy, Wm, Wy, UtM, UtY, WtM, WtY);
    build_wc2<<<(2 * 512 * 12 + 255) / 256, 256, 0, stream>>>(Wm, Wy, Wc2M, Wc2Y);
    cond_transpose<<<(SEQ * B_TOT + 255) / 256, 256, 0, stream>>>(cond, condT4);
    build_heads<<<(32 * 512 + 16 * 512 + SEQ * 32 + SEQ * 16 + 255) / 256, 256, 0, stream>>>(
        Whm, bhm, Why, bhy, WhmT, WhyT, tscm, tscy);

    dim3 ggrid(B_TOT / 128, ZW / 128, 2);
    gemm_step<0><<<ggrid, 256, 0, stream>>>(hM0, hM0, WtM, WtY, nullptr, nullptr,
                                            nullptr, nullptr, bm, by_, nullptr, nullptr,
                                            nullptr, nullptr, xwM, xwY, condT4, 0);

    for (int t = 0; t < SEQ; ++t) {
        const int a = t & 1, b = (t + 1) & 1;
        gemm_step<1><<<ggrid, 256, 0, stream>>>(hM[a], hY[a], UtM, UtY, xwM, xwY,
                                                Wc2M, Wc2Y, nullptr, nullptr, cMb, cYb,
                                                hM[b], hY[b], nullptr, nullptr, condT4, t);
        heads_step<<<B_TOT / 32, 128, 0, stream>>>(hM[b], hY[b], WhmT, WhyT, tscm, tscy, out, t);
    }
}

// Round 8
// 7164.256 us; speedup vs baseline: 1.1168x; 1.1168x over previous
//
#include <hip/hip_runtime.h>

typedef __bf16 bf16;
typedef __attribute__((ext_vector_type(8))) __bf16 bf16x8;
typedef __attribute__((ext_vector_type(4))) __bf16 bf16x4;
typedef __attribute__((ext_vector_type(4))) float f32x4;
typedef __attribute__((ext_vector_type(4))) int i32x4;

#define B_TOT 16384
#define SEQ 50
#define DH 512
#define ZW 2048  // 4*DH
#define NT 16    // K-tiles of 32 (K = 512)

#define MFMA16(a, b, c) __builtin_amdgcn_mfma_f32_16x16x32_bf16(a, b, c, 0, 0, 0)

__device__ __forceinline__ float fsigm(float x) {
    return __fdividef(1.0f, 1.0f + __expf(-x));
}
__device__ __forceinline__ float ftanh(float x) {
    float e = __expf(2.0f * x);
    return 1.0f - __fdividef(2.0f, e + 1.0f);
}

// ---------------------------------------------------------------------------
// Fragment layout (both GEMM operands):
//   frag[((rg*16 + kt)*64 + fq*16 + fr)]*8 + e  <->  element [rg*16+fr][kt*32+fq*8+e]
// Strides: rg = 16384 B, kt = 1024 B, lane-slot = 16 B.
// A wave's fragment load = 64 lanes x 16 B = 1 KB contiguous.
// ---------------------------------------------------------------------------

__global__ void init_state(const float* __restrict__ sh,
                           bf16* __restrict__ h0m, bf16* __restrict__ h0y) {
    size_t i = (size_t)blockIdx.x * 256 + threadIdx.x;
    int row = i >> 9, k = i & 511;
    size_t off = (((size_t)(row >> 4) * 16 + (k >> 5)) * 64 + ((k >> 3) & 3) * 16 +
                  (row & 15)) * 8 + (k & 7);
    bf16 hb = (bf16)sh[i];
    h0m[off] = hb;
    h0y[off] = hb;
}

// c3[row>>2][hcol][row&3] f32, duplicated into cM and cY.
__global__ void build_c3(const float* __restrict__ src,
                         float* __restrict__ dM, float* __restrict__ dY) {
    size_t i = (size_t)blockIdx.x * 256 + threadIdx.x;
    int row = i >> 9, hcol = i & 511;
    float v = src[i];
    size_t o = ((size_t)(row >> 2) * 512 + hcol) * 4 + (row & 3);
    dM[o] = v;
    dY[o] = v;
}

// Column reorder: col' = jb*64 + gate*16 + jj  <->  orig col = gate*512 + jb*16 + jj
__device__ __forceinline__ int orig_col(int colp) {
    return ((colp >> 4) & 3) * 512 + ((colp >> 6) << 4) + (colp & 15);
}

// B-operands (U^T, W^T) in fragment layout (cb = column-group).
__global__ void reorder_weights(const float* __restrict__ Um, const float* __restrict__ Uy,
                                const float* __restrict__ Wm, const float* __restrict__ Wy,
                                bf16* __restrict__ UtM, bf16* __restrict__ UtY,
                                bf16* __restrict__ WtM, bf16* __restrict__ WtY) {
    int idx = blockIdx.x * 256 + threadIdx.x;
    int which = idx >> 20;
    int r = idx & ((1 << 20) - 1);
    int colp = r >> 9, k = r & 511;
    int orig = orig_col(colp);
    const float* src = which == 0 ? Um : which == 1 ? Uy : which == 2 ? Wm : Wy;
    bf16* dst = which == 0 ? UtM : which == 1 ? UtY : which == 2 ? WtM : WtY;
    int cb = colp >> 4, fr = colp & 15;
    int kt = k >> 5, fq = (k >> 3) & 3, e = k & 7;
    int lane = fq * 16 + fr;
    dst[(((size_t)(cb * 16 + kt) * 64 + lane) << 3) + e] = (bf16)src[(size_t)k * ZW + orig];
}

// Wc2[hcol][r(3)][g(4)] f32
__global__ void build_wc2(const float* __restrict__ Wm, const float* __restrict__ Wy,
                          float* __restrict__ Wc2M, float* __restrict__ Wc2Y) {
    int idx = blockIdx.x * 256 + threadIdx.x;
    if (idx >= 2 * 512 * 12) return;
    int which = idx / 6144;
    int r2 = idx % 6144;
    int hcol = r2 / 12, rg = r2 % 12;
    int r = rg >> 2, g = rg & 3;
    const float* src = which ? Wy : Wm;
    float* dst = which ? Wc2Y : Wc2M;
    dst[hcol * 12 + rg] = src[(size_t)(512 + r) * ZW + g * 512 + hcol];
}

// condT4[t][row][4] f32
__global__ void cond_transpose(const float* __restrict__ cond, float* __restrict__ condT4) {
    int idx = blockIdx.x * 256 + threadIdx.x;
    if (idx >= SEQ * B_TOT) return;
    int t = idx / B_TOT, row = idx % B_TOT;
    const float* s = cond + ((size_t)row * SEQ + t) * 3;
    f32x4 v = {s[0], s[1], s[2], 0.f};
    *(f32x4*)(condT4 + (size_t)idx * 4) = v;
}

__global__ void build_heads(const float* __restrict__ Whm, const float* __restrict__ bhm,
                            const float* __restrict__ Why, const float* __restrict__ bhy,
                            bf16* __restrict__ WhmT, bf16* __restrict__ WhyT,
                            float* __restrict__ tscm, float* __restrict__ tscy) {
    int i = blockIdx.x * 256 + threadIdx.x;
    const int N1 = 32 * 512, N2 = 16 * 512, N3 = SEQ * 32, N4 = SEQ * 16;
    if (i < N1) {
        int n = i >> 9, k = i & 511;
        WhmT[i] = (bf16)(n < 30 ? Whm[k * 30 + n] : 0.f);
    } else if (i < N1 + N2) {
        int j = i - N1;
        int n = j >> 9, k = j & 511;
        WhyT[j] = (bf16)(n < 15 ? Why[k * 15 + n] : 0.f);
    } else if (i < N1 + N2 + N3) {
        int j = i - (N1 + N2);
        int tt = j >> 5, col = j & 31;
        float v = 0.f;
        if (col < 30) {
            v = bhm[col];
            for (int s = 0; s <= tt; ++s) v += Whm[(512 + s) * 30 + col];
        }
        tscm[j] = v;
    } else if (i < N1 + N2 + N3 + N4) {
        int j = i - (N1 + N2 + N3);
        int tt = j >> 4, col = j & 15;
        float v = 0.f;
        if (col < 15) {
            v = bhy[col];
            for (int s = 0; s <= tt; ++s) v += Why[(512 + s) * 15 + col];
        }
        tscy[j] = v;
    }
}

// ---------------------------------------------------------------------------
// Main GEMM: 128x128 tile, BK=32, 4 waves (2x2). NO LDS, NO BARRIERS.
// Both operands in fragment layout; A- and B-fragments loaded via inline-asm
// global_load_dwordx4 (1 KB coalesced per wave-load), double-buffered in
// registers, depth-2 prefetch, counted vmcnt(8). Waves free-run.
// MODE 0: xw precompute -> xw3[row>>2][hcol][j][g] bf16.
// MODE 1: LSTM step; coalesced epilogue (xw3/c3 chunked layouts), h written
//         in fragment layout for the next step's A.
// ---------------------------------------------------------------------------

#define WAIT_VM(n)                                                  \
    do {                                                            \
        asm volatile("s_waitcnt vmcnt(" #n ")" ::: "memory");       \
        __builtin_amdgcn_sched_barrier(0);                          \
    } while (0)

template <int MODE>
__global__ __launch_bounds__(256, 3) void gemm_step(
    const bf16* __restrict__ Am, const bf16* __restrict__ Ay,
    const bf16* __restrict__ BtM, const bf16* __restrict__ BtY,
    const bf16* __restrict__ xwM, const bf16* __restrict__ xwY,
    const float* __restrict__ Wc2M, const float* __restrict__ Wc2Y,
    const float* __restrict__ biasM, const float* __restrict__ biasY,
    float* __restrict__ cM, float* __restrict__ cY,
    bf16* __restrict__ hoM, bf16* __restrict__ hoY,
    bf16* __restrict__ xoM, bf16* __restrict__ xoY,
    const float* __restrict__ condT4, int t) {
    const int tid = threadIdx.x;
    const int wave = tid >> 6, lane = tid & 63;
    // XCD-aware swizzle: each XCD owns a 16-wide bx band, iterating all by.
    const int lin = blockIdx.y * 128 + blockIdx.x;  // 0..2047
    const int xcd = lin & 7, jj2 = lin >> 3;
    const int bx = xcd * 16 + (jj2 >> 4);
    const int by = jj2 & 15;
    const int brow = bx * 128;
    const int bz = blockIdx.z;
    const bf16* A = bz ? Ay : Am;     // fragment layout
    const bf16* Bt = bz ? BtY : BtM;  // fragment layout

    const int fr = lane & 15, fq = lane >> 4;
    const int wr = wave >> 1, wc = wave & 1;

    // fragment bases (byte addresses); rg stride 16384 B, kt stride 1024 B.
    // addr(m|n, kt) = base + (m|n)*16384 + kt*1024
    const uint64_t abase =
        (uint64_t)(const char*)A + (uint64_t)(bx * 8 + wr * 4) * 16384 + lane * 16;
    const uint64_t bbase =
        (uint64_t)(const char*)Bt + (uint64_t)(by * 8 + wc * 4) * 16384 + lane * 16;

    f32x4 acc[4][4];
#pragma unroll
    for (int m = 0; m < 4; ++m)
#pragma unroll
        for (int n = 0; n < 4; ++n) acc[m][n] = (f32x4){0.f, 0.f, 0.f, 0.f};

    i32x4 afr[2][4], bfr[2][4];

#define AGLOAD(bank, kts)                                                         \
    do {                                                                          \
        uint64_t _a = abase + (uint64_t)(kts) * 1024;                             \
        asm volatile("global_load_dwordx4 %0, %1, off"                            \
                     : "=&v"(afr[bank][0]) : "v"(_a) : "memory");                 \
        asm volatile("global_load_dwordx4 %0, %1, off"                            \
                     : "=&v"(afr[bank][1]) : "v"(_a + 16384) : "memory");         \
        asm volatile("global_load_dwordx4 %0, %1, off"                            \
                     : "=&v"(afr[bank][2]) : "v"(_a + 32768) : "memory");         \
        asm volatile("global_load_dwordx4 %0, %1, off"                            \
                     : "=&v"(afr[bank][3]) : "v"(_a + 49152) : "memory");         \
    } while (0)
#define BGLOAD(bank, kts)                                                         \
    do {                                                                          \
        uint64_t _b = bbase + (uint64_t)(kts) * 1024;                             \
        asm volatile("global_load_dwordx4 %0, %1, off"                            \
                     : "=&v"(bfr[bank][0]) : "v"(_b) : "memory");                 \
        asm volatile("global_load_dwordx4 %0, %1, off"                            \
                     : "=&v"(bfr[bank][1]) : "v"(_b + 16384) : "memory");         \
        asm volatile("global_load_dwordx4 %0, %1, off"                            \
                     : "=&v"(bfr[bank][2]) : "v"(_b + 32768) : "memory");         \
        asm volatile("global_load_dwordx4 %0, %1, off"                            \
                     : "=&v"(bfr[bank][3]) : "v"(_b + 49152) : "memory");         \
    } while (0)

    // prologue: tiles 0 and 1 in flight (16 loads)
    AGLOAD(0, 0);
    BGLOAD(0, 0);
    AGLOAD(1, 1);
    BGLOAD(1, 1);

#pragma unroll
    for (int kt = 0; kt < NT; ++kt) {
        if (kt < NT - 1) {
            WAIT_VM(8);  // retire tile kt's 8 loads; tile kt+1 stays in flight
        } else {
            WAIT_VM(0);
        }
        __builtin_amdgcn_s_setprio(1);
#pragma unroll
        for (int m = 0; m < 4; ++m)
#pragma unroll
            for (int n = 0; n < 4; ++n)
                acc[m][n] = MFMA16(__builtin_bit_cast(bf16x8, afr[kt & 1][m]),
                                   __builtin_bit_cast(bf16x8, bfr[kt & 1][n]), acc[m][n]);
        __builtin_amdgcn_s_setprio(0);
        __builtin_amdgcn_sched_barrier(0);
        if (kt + 2 < NT) {
            AGLOAD(kt & 1, kt + 2);
            BGLOAD(kt & 1, kt + 2);
        }
    }
#undef AGLOAD
#undef BGLOAD

    const int jb = by * 2 + wc;     // 0..31
    const int hcol = jb * 16 + fr;  // 0..511
    const int rowbase = brow + wr * 64 + fq * 4;
    const int rb0 = (rowbase >> 2);  // row>>2 base; +m*4 per m

    if (MODE == 0) {
        const float* bias = bz ? biasY : biasM;
        bf16* XO = bz ? xoY : xoM;
        float b0 = bias[hcol], b1 = bias[512 + hcol], b2 = bias[1024 + hcol],
              b3 = bias[1536 + hcol];
#pragma unroll
        for (int m = 0; m < 4; ++m) {
            bf16x8 v0, v1;
#pragma unroll
            for (int j = 0; j < 2; ++j) {
                v0[j * 4 + 0] = (bf16)(acc[m][0][j] + b0);
                v0[j * 4 + 1] = (bf16)(acc[m][1][j] + b1);
                v0[j * 4 + 2] = (bf16)(acc[m][2][j] + b2);
                v0[j * 4 + 3] = (bf16)(acc[m][3][j] + b3);
            }
#pragma unroll
            for (int j = 2; j < 4; ++j) {
                v1[(j - 2) * 4 + 0] = (bf16)(acc[m][0][j] + b0);
                v1[(j - 2) * 4 + 1] = (bf16)(acc[m][1][j] + b1);
                v1[(j - 2) * 4 + 2] = (bf16)(acc[m][2][j] + b2);
                v1[(j - 2) * 4 + 3] = (bf16)(acc[m][3][j] + b3);
            }
            bf16* o = XO + ((size_t)(rb0 + m * 4) * 512 + hcol) * 16;
            *(bf16x8*)(o) = v0;
            *(bf16x8*)(o + 8) = v1;
        }
    } else {
        float* Cb = bz ? cY : cM;
        bf16* Ho = bz ? hoY : hoM;
        const bf16* xw = bz ? xwY : xwM;
        const float* Wc2 = bz ? Wc2Y : Wc2M;
        f32x4 wcv0 = *(const f32x4*)(Wc2 + hcol * 12);
        f32x4 wcv1 = *(const f32x4*)(Wc2 + hcol * 12 + 4);
        f32x4 wcv2 = *(const f32x4*)(Wc2 + hcol * 12 + 8);
        // h-frag store base: rg = (brow>>4) + wr*4 + m; kt = jb>>1;
        // fqp = (jb&1)*2 + (fr>>3); fr_frag = fq*4 + j; e = fr&7.
        const int ktc = jb >> 1;
        const int fqp = (jb & 1) * 2 + (fr >> 3);
        bf16* hob = Ho + (((size_t)((brow >> 4) + wr * 4) * 16 + ktc) * 64 + fqp * 16 +
                          fq * 4) * 8 + (fr & 7);
#pragma unroll
        for (int m = 0; m < 4; ++m) {
            const size_t co = ((size_t)(rb0 + m * 4) * 512 + hcol);
            const bf16* xp = xw + co * 16;
            bf16x8 xv0 = *(const bf16x8*)(xp);
            bf16x8 xv1 = *(const bf16x8*)(xp + 8);
            f32x4 cvm = *(const f32x4*)(Cb + co * 4);
            const int row0 = rowbase + m * 16;
            f32x4 cd[4];
#pragma unroll
            for (int j = 0; j < 4; ++j)
                cd[j] = *(const f32x4*)(condT4 + ((size_t)t * B_TOT + row0 + j) * 4);
            f32x4 cnew;
            bf16* hom = hob + (size_t)m * 16 * 64 * 8;
#pragma unroll
            for (int j = 0; j < 4; ++j) {
                float z[4];
#pragma unroll
                for (int g = 0; g < 4; ++g) {
                    float xwv = (j < 2) ? (float)xv0[j * 4 + g] : (float)xv1[(j - 2) * 4 + g];
                    z[g] = acc[m][g][j] + xwv + cd[j][0] * wcv0[g] + cd[j][1] * wcv1[g] +
                           cd[j][2] * wcv2[g];
                }
                float ii = fsigm(z[0]);
                float ff = fsigm(z[1]);
                float gg = ftanh(z[2]);
                float oo = fsigm(z[3]);
                float cn = ff * cvm[j] + ii * gg;
                cnew[j] = cn;
                hom[j * 8] = (bf16)(oo * ftanh(cn));
            }
            *(f32x4*)(Cb + co * 4) = cnew;
        }
    }
}

// ---------------------------------------------------------------------------
// Heads: 512 blocks x 128 threads; 2 waves/block, 16 rows per wave.
// h is in fragment layout -> 1 KB coalesced loads.
// ---------------------------------------------------------------------------
__global__ __launch_bounds__(128) void heads_step(
    const bf16* __restrict__ hm, const bf16* __restrict__ hy,
    const bf16* __restrict__ WhmT, const bf16* __restrict__ WhyT,
    const float* __restrict__ tscm, const float* __restrict__ tscy,
    float* __restrict__ out, int t) {
    __shared__ float zbuf[2 * 768];
    const int tid = threadIdx.x, wave = tid >> 6, lane = tid & 63;
    const int fr = lane & 15, fq = lane >> 4;
    const int rbase = blockIdx.x * 32 + wave * 16;
    const int rg = rbase >> 4;

    f32x4 am0 = {0.f, 0.f, 0.f, 0.f}, am1 = {0.f, 0.f, 0.f, 0.f}, ay0 = {0.f, 0.f, 0.f, 0.f};

    for (int kt = 0; kt < 16; ++kt) {
        const size_t ao = ((size_t)(rg * 16 + kt) * 64 + lane) * 8;
        bf16x8 a0 = *(const bf16x8*)(hm + ao);
        bf16x8 y0 = *(const bf16x8*)(hy + ao);
        const int k0 = kt * 32;
        const size_t bo = (size_t)fr * DH + k0 + fq * 8;
        bf16x8 b0 = *(const bf16x8*)(WhmT + bo);
        bf16x8 b1 = *(const bf16x8*)(WhmT + bo + 16 * DH);
        bf16x8 yb = *(const bf16x8*)(WhyT + bo);
        am0 = MFMA16(a0, b0, am0);
        am1 = MFMA16(a0, b1, am1);
        ay0 = MFMA16(y0, yb, ay0);
    }

    float* zm = zbuf + wave * 768;  // [16][32]
    float* zy = zm + 512;           // [16][16]
#pragma unroll
    for (int j = 0; j < 4; ++j) {
        int rl = fq * 4 + j;
        zm[rl * 32 + fr] = am0[j] + tscm[t * 32 + fr];
        zm[rl * 32 + 16 + fr] = am1[j] + tscm[t * 32 + 16 + fr];
        zy[rl * 16 + fr] = ay0[j] + tscy[t * 16 + fr];
    }
    __syncthreads();

    const int r = lane & 15;
    const size_t grow = (size_t)rbase + r;
    if (lane < 16) {
        float z[30];
#pragma unroll
        for (int i = 0; i < 30; ++i) z[i] = zm[r * 32 + i];
        float* o = out + (grow * SEQ + t) * 30;
        float mx = z[0];
#pragma unroll
        for (int i = 1; i < 5; ++i) mx = fmaxf(mx, z[i]);
        float e[5], s = 0.f;
#pragma unroll
        for (int i = 0; i < 5; ++i) {
            e[i] = __expf(z[i] - mx);
            s += e[i];
        }
        float inv = __fdividef(1.f, s);
#pragma unroll
        for (int i = 0; i < 5; ++i) o[i] = e[i] * inv;
#pragma unroll
        for (int i = 5; i < 10; ++i) o[i] = z[i];
#pragma unroll
        for (int i = 10; i < 15; ++i) o[i] = __expf(z[i]);
#pragma unroll
        for (int i = 15; i < 20; ++i) o[i] = z[i];
#pragma unroll
        for (int i = 20; i < 25; ++i) o[i] = __expf(z[i]);
#pragma unroll
        for (int i = 25; i < 30; ++i) o[i] = ftanh(z[i]);
    } else if (lane < 32) {
        float z[15];
#pragma unroll
        for (int i = 0; i < 15; ++i) z[i] = zy[r * 16 + i];
        float* o = out + (size_t)B_TOT * SEQ * 30 + (grow * SEQ + t) * 15;
        float mx = z[0];
#pragma unroll
        for (int i = 1; i < 5; ++i) mx = fmaxf(mx, z[i]);
        float e[5], s = 0.f;
#pragma unroll
        for (int i = 0; i < 5; ++i) {
            e[i] = __expf(z[i] - mx);
            s += e[i];
        }
        float inv = __fdividef(1.f, s);
#pragma unroll
        for (int i = 0; i < 5; ++i) o[i] = e[i] * inv;
#pragma unroll
        for (int i = 5; i < 10; ++i) o[i] = z[i];
#pragma unroll
        for (int i = 10; i < 15; ++i) o[i] = __expf(z[i]);
    }
}

// ---------------------------------------------------------------------------
extern "C" void kernel_launch(void* const* d_in, const int* in_sizes, int n_in,
                              void* d_out, int out_size, void* d_ws, size_t ws_size,
                              hipStream_t stream) {
    const float* cond = (const float*)d_in[0];
    const float* sh = (const float*)d_in[1];
    const float* sc = (const float*)d_in[2];
    const float* Wm = (const float*)d_in[3];
    const float* Um = (const float*)d_in[4];
    const float* bm = (const float*)d_in[5];
    const float* Whm = (const float*)d_in[6];
    const float* bhm = (const float*)d_in[7];
    const float* Wy = (const float*)d_in[8];
    const float* Uy = (const float*)d_in[9];
    const float* by_ = (const float*)d_in[10];
    const float* Why = (const float*)d_in[11];
    const float* bhy = (const float*)d_in[12];
    float* out = (float*)d_out;

    char* p = (char*)d_ws;
    auto take = [&](size_t bytes) {
        char* r = p;
        p += (bytes + 255) & ~(size_t)255;
        return r;
    };
    bf16* UtM = (bf16*)take((size_t)ZW * DH * 2);
    bf16* UtY = (bf16*)take((size_t)ZW * DH * 2);
    bf16* WtM = (bf16*)take((size_t)ZW * DH * 2);
    bf16* WtY = (bf16*)take((size_t)ZW * DH * 2);
    float* Wc2M = (float*)take(512 * 12 * 4);
    float* Wc2Y = (float*)take(512 * 12 * 4);
    bf16* WhmT = (bf16*)take(32 * DH * 2);
    bf16* WhyT = (bf16*)take(16 * DH * 2);
    float* tscm = (float*)take(SEQ * 32 * 4);
    float* tscy = (float*)take(SEQ * 16 * 4);
    float* condT4 = (float*)take((size_t)SEQ * B_TOT * 4 * 4);
    bf16* xwM = (bf16*)take((size_t)B_TOT * ZW * 2);
    bf16* xwY = (bf16*)take((size_t)B_TOT * ZW * 2);
    bf16* hM0 = (bf16*)take((size_t)B_TOT * DH * 2);
    bf16* hM1 = (bf16*)take((size_t)B_TOT * DH * 2);
    bf16* hY0 = (bf16*)take((size_t)B_TOT * DH * 2);
    bf16* hY1 = (bf16*)take((size_t)B_TOT * DH * 2);
    float* cMb = (float*)take((size_t)B_TOT * DH * 4);
    float* cYb = (float*)take((size_t)B_TOT * DH * 4);
    bf16* hM[2] = {hM0, hM1};
    bf16* hY[2] = {hY0, hY1};

    init_state<<<(B_TOT * DH) / 256, 256, 0, stream>>>(sh, hM0, hY0);
    build_c3<<<(B_TOT * DH) / 256, 256, 0, stream>>>(sc, cMb, cYb);
    reorder_weights<<<(4 * ZW * DH) / 256, 256, 0, stream>>>(Um, Uy, Wm, Wy, UtM, UtY, WtM, WtY);
    build_wc2<<<(2 * 512 * 12 + 255) / 256, 256, 0, stream>>>(Wm, Wy, Wc2M, Wc2Y);
    cond_transpose<<<(SEQ * B_TOT + 255) / 256, 256, 0, stream>>>(cond, condT4);
    build_heads<<<(32 * 512 + 16 * 512 + SEQ * 32 + SEQ * 16 + 255) / 256, 256, 0, stream>>>(
        Whm, bhm, Why, bhy, WhmT, WhyT, tscm, tscy);

    dim3 ggrid(B_TOT / 128, ZW / 128, 2);
    gemm_step<0><<<ggrid, 256, 0, stream>>>(hM0, hM0, WtM, WtY, nullptr, nullptr,
                                            nullptr, nullptr, bm, by_, nullptr, nullptr,
                                            nullptr, nullptr, xwM, xwY, condT4, 0);

    for (int t = 0; t < SEQ; ++t) {
        const int a = t & 1, b = (t + 1) & 1;
        gemm_step<1><<<ggrid, 256, 0, stream>>>(hM[a], hY[a], UtM, UtY, xwM, xwY,
                                                Wc2M, Wc2Y, nullptr, nullptr, cMb, cYb,
                                                hM[b], hY[b], nullptr, nullptr, condT4, t);
        heads_step<<<B_TOT / 32, 128, 0, stream>>>(hM[b], hY[b], WhmT, WhyT, tscm, tscy, out, t);
    }
}